// Round 5
// baseline (644.514 us; speedup 1.0000x reference)
//
#include <hip/hip_runtime.h>
#include <hip/hip_bf16.h>

#define NEG_SLOPE 0.2f
#define BUK_SHIFT 9
#define BUK_SIZE 512
#define BUK_CAP 16384  // max edges per 512-node bucket (expected ~8.2K, sigma ~91)

// ---------------- binned CSR build ----------------

__global__ void k_zero(int* g_cnt, int nb) {
    int i = blockIdx.x * blockDim.x + threadIdx.x;
    if (i < nb) g_cnt[i] = 0;
}

// Tile of 4096 edges per block. LDS bucket counts -> one chunk-reserve atomic per
// (block,bucket) -> append packed (src<<9 | dst&511) to bucket. Appends are
// frontier-sequential per bucket => dense 64B lines (vs 4B random scatter).
__launch_bounds__(256)
__global__ void k_binscatter(const int* __restrict__ ei, int* g_cnt, int* buckets,
                             int E, int nb) {
    __shared__ int lcnt[256], lbase[256], lcur[256];
    int t = threadIdx.x;
    if (t < nb) {
        lcnt[t] = 0;
        lcur[t] = 0;
    }
    __syncthreads();
    int tile0 = blockIdx.x * 4096;
    int pk[16], bk[16];
#pragma unroll
    for (int k = 0; k < 16; k++) {
        int idx = tile0 + k * 256 + t;
        bk[k] = -1;
        if (idx < E) {
            int s = ei[idx];
            int d = ei[E + idx];
            bk[k] = d >> BUK_SHIFT;
            pk[k] = (s << BUK_SHIFT) | (d & (BUK_SIZE - 1));
            atomicAdd(&lcnt[bk[k]], 1);
        }
    }
    __syncthreads();
    if (t < nb && lcnt[t] > 0) lbase[t] = atomicAdd(&g_cnt[t], lcnt[t]);
    __syncthreads();
#pragma unroll
    for (int k = 0; k < 16; k++) {
        if (bk[k] >= 0) {
            int p = lbase[bk[k]] + atomicAdd(&lcur[bk[k]], 1);
            if (p < BUK_CAP) buckets[(bk[k] << 14) + p] = pk[k];
        }
    }
}

// exclusive scan over nb bucket totals (edges + self-loops), nb <= 256
__global__ void k_bucket_scan(const int* __restrict__ g_cnt, int* bucket_off, int nb, int n) {
    __shared__ int s[256];
    int t = threadIdx.x;
    int selfc = 0;
    if (t < nb) {
        int lo = t * BUK_SIZE;
        selfc = min(BUK_SIZE, n - lo);
    }
    int v = (t < nb) ? (min(g_cnt[t], BUK_CAP) + selfc) : 0;
    s[t] = v;
    __syncthreads();
    for (int off = 1; off < 256; off <<= 1) {
        int x = (t >= off) ? s[t - off] : 0;
        __syncthreads();
        s[t] += x;
        __syncthreads();
    }
    if (t < nb) bucket_off[t] = s[t] - v;  // exclusive
    if (t == nb - 1) bucket_off[nb] = s[t];
}

// One block per bucket: local per-node count + scan + scatter into the bucket's
// contiguous csr window (L2-resident, ~35KB). Also emits csr_ptr and self-loops.
__launch_bounds__(512)
__global__ void k_csr(const int* __restrict__ g_cnt, const int* __restrict__ bucket_off,
                      const int* __restrict__ buckets, int* csr_ptr, int* csr_src,
                      int n, int nb) {
    __shared__ int lcnt[512], lsc[512], lcur[512];
    int b = blockIdx.x;
    int t = threadIdx.x;
    int nodes = min(BUK_SIZE, n - b * BUK_SIZE);
    int cnt = min(g_cnt[b], BUK_CAP);
    int boff = bucket_off[b];
    const int* bp = &buckets[b << 14];
    lcnt[t] = 0;
    __syncthreads();
    for (int i = t; i < cnt; i += 512) atomicAdd(&lcnt[bp[i] & (BUK_SIZE - 1)], 1);
    __syncthreads();
    int myc = (t < nodes) ? (lcnt[t] + 1) : 0;
    lsc[t] = myc;
    __syncthreads();
    for (int off = 1; off < 512; off <<= 1) {
        int x = (t >= off) ? lsc[t - off] : 0;
        __syncthreads();
        lsc[t] += x;
        __syncthreads();
    }
    int excl = lsc[t] - myc;
    lcur[t] = excl;
    if (t < nodes) csr_ptr[b * BUK_SIZE + t] = boff + excl;
    if (b == nb - 1 && t == 0) csr_ptr[n] = bucket_off[nb];
    __syncthreads();
    for (int i = t; i < cnt; i += 512) {
        int v = bp[i];
        int ld = v & (BUK_SIZE - 1);
        int p = atomicAdd(&lcur[ld], 1);
        csr_src[boff + p] = v >> BUK_SHIFT;
    }
    if (t < nodes) {
        int p = atomicAdd(&lcur[t], 1);
        csr_src[boff + p] = b * BUK_SIZE + t;  // self loop
    }
}

// ---------------- GEMM + fused attention logits ----------------

template <int M>
__launch_bounds__(256)
__global__ void k_gemm(const float* __restrict__ X, const float* __restrict__ W,
                       const float* __restrict__ asrc, const float* __restrict__ adst,
                       float* __restrict__ Hout, float* __restrict__ als,
                       float* __restrict__ ald, int n) {
    const int WS = M + 4;
    const int CPT = M / 16;
    __shared__ float Xs[128 * 36];
    __shared__ float Ws[32 * (M + 4)];
    int t = threadIdx.x;
    int c_grp = t & 15;
    int r_grp = t >> 4;
    int c0 = c_grp * CPT;
    int rb = blockIdx.x * 128;

    float acc[8][CPT];
#pragma unroll
    for (int i = 0; i < 8; i++)
#pragma unroll
        for (int j = 0; j < CPT; j++) acc[i][j] = 0.f;

    for (int p = 0; p < 4; p++) {
        __syncthreads();
        {
            const int TPR = M / 4;
            int wc4 = t % TPR;
            int wr0 = t / TPR;
            for (int wr = wr0; wr < 32; wr += 256 / TPR) {
                float4 v = *(const float4*)&W[(size_t)(p * 32 + wr) * M + wc4 * 4];
                *(float4*)&Ws[wr * WS + wc4 * 4] = v;
            }
        }
        {
            int k4 = t & 7;
            int r0 = t >> 3;
            for (int r = r0; r < 128; r += 32) {
                int grow = rb + r;
                float4 v = make_float4(0.f, 0.f, 0.f, 0.f);
                if (grow < n) v = *(const float4*)&X[(size_t)grow * 128 + p * 32 + k4 * 4];
                *(float4*)&Xs[r * 36 + k4 * 4] = v;
            }
        }
        __syncthreads();
#pragma unroll 4
        for (int k = 0; k < 32; k++) {
            float xv[8];
#pragma unroll
            for (int i = 0; i < 8; i++) xv[i] = Xs[(r_grp + 16 * i) * 36 + k];
            float wv[CPT];
#pragma unroll
            for (int j4 = 0; j4 < CPT / 4; j4++)
                *(float4*)&wv[j4 * 4] = *(const float4*)&Ws[k * WS + c0 + j4 * 4];
#pragma unroll
            for (int i = 0; i < 8; i++)
#pragma unroll
                for (int j = 0; j < CPT; j++) acc[i][j] = fmaf(xv[i], wv[j], acc[i][j]);
        }
    }

    float av[CPT], dv[CPT];
#pragma unroll
    for (int j = 0; j < CPT; j++) {
        av[j] = asrc[c0 + j];
        dv[j] = adst[c0 + j];
    }
#pragma unroll
    for (int i = 0; i < 8; i++) {
        int row = rb + r_grp + 16 * i;
        float ps = 0.f, pd = 0.f;
#pragma unroll
        for (int j = 0; j < CPT; j++) {
            ps = fmaf(acc[i][j], av[j], ps);
            pd = fmaf(acc[i][j], dv[j], pd);
        }
        const int RED = (M == 128) ? 4 : 8;
        for (int m = 1; m <= RED; m <<= 1) {
            ps += __shfl_xor(ps, m);
            pd += __shfl_xor(pd, m);
        }
        if (row < n) {
#pragma unroll
            for (int j4 = 0; j4 < CPT / 4; j4++)
                *(float4*)&Hout[(size_t)row * M + c0 + j4 * 4] =
                    make_float4(acc[i][j4 * 4], acc[i][j4 * 4 + 1], acc[i][j4 * 4 + 2],
                                acc[i][j4 * 4 + 3]);
            if (M == 128) {
                if ((c_grp & 7) == 0) {
                    int hd = c_grp >> 3;
                    als[(size_t)row * 2 + hd] = ps;
                    ald[(size_t)row * 2 + hd] = pd;
                }
            } else {
                if (c_grp == 0) {
                    als[row] = ps;
                    ald[row] = pd;
                }
            }
        }
    }
}

// ---------------- aggregation M=128 ----------------
// One wave per node. Per 64-edge block: lanes compute (src, ex0, ex1) and stage
// into LDS (wave-synchronous, zero-padded). Inner loop: half-waves read edge meta
// via broadcast ds_read (free, 2 addrs) and gather H rows with 4 loads in flight.

template <int RELU>
__launch_bounds__(256)
__global__ void k_agg128(const int* __restrict__ ptr, const int* __restrict__ srcv,
                         const float* __restrict__ Hf, const float* __restrict__ als,
                         const float* __restrict__ ald, const float* __restrict__ bias,
                         float* __restrict__ Out, int n) {
    __shared__ float4 meta_s[4][64];
    int tid = threadIdx.x;
    int wslot = tid >> 6;
    int lane = tid & 63;
    int wid = blockIdx.x * 4 + wslot;
    if (wid >= n) return;
    float4* mp = meta_s[wslot];
    int start = ptr[wid], end = ptr[wid + 1];
    float2 adv = *(const float2*)&ald[(size_t)wid * 2];
    int hi = lane >> 5;
    int myq = (lane >> 4) & 1;
    int colbase = (lane & 31) * 4;
    float z0 = 0.f, z1 = 0.f;
    float4 a1v = make_float4(0.f, 0.f, 0.f, 0.f);
    float4 a2v = make_float4(0.f, 0.f, 0.f, 0.f);
    float4 a3v = make_float4(0.f, 0.f, 0.f, 0.f);
    float4 a4v = make_float4(0.f, 0.f, 0.f, 0.f);

    for (int base = start; base < end; base += 64) {
        int i = base + lane;
        int s_l = 0;
        float ex0 = 0.f, ex1 = 0.f;
        if (i < end) {
            s_l = srcv[i];
            float2 av = *(const float2*)&als[(size_t)s_l * 2];
            float e0 = av.x + adv.x;
            e0 = e0 > 0.f ? e0 : NEG_SLOPE * e0;
            ex0 = __expf(e0);
            float e1 = av.y + adv.y;
            e1 = e1 > 0.f ? e1 : NEG_SLOPE * e1;
            ex1 = __expf(e1);
        }
        z0 += ex0;
        z1 += ex1;
        mp[lane] = make_float4(__int_as_float(s_l), ex0, ex1, 0.f);
        int cntj = min(64, end - base);
        int cnt4 = (cntj + 3) & ~3;  // zero-padded meta makes extras harmless
        int jp = 0;
        for (; jp + 8 <= cnt4; jp += 8) {
            float4 m1 = mp[jp + hi];
            float4 m2 = mp[jp + 2 + hi];
            float4 m3 = mp[jp + 4 + hi];
            float4 m4 = mp[jp + 6 + hi];
            int r1 = __float_as_int(m1.x);
            int r2 = __float_as_int(m2.x);
            int r3 = __float_as_int(m3.x);
            int r4 = __float_as_int(m4.x);
            float w1 = myq ? m1.z : m1.y;
            float w2 = myq ? m2.z : m2.y;
            float w3 = myq ? m3.z : m3.y;
            float w4 = myq ? m4.z : m4.y;
            float4 h1 = *(const float4*)&Hf[(size_t)r1 * 128 + colbase];
            float4 h2 = *(const float4*)&Hf[(size_t)r2 * 128 + colbase];
            float4 h3 = *(const float4*)&Hf[(size_t)r3 * 128 + colbase];
            float4 h4 = *(const float4*)&Hf[(size_t)r4 * 128 + colbase];
            a1v.x = fmaf(w1, h1.x, a1v.x);
            a1v.y = fmaf(w1, h1.y, a1v.y);
            a1v.z = fmaf(w1, h1.z, a1v.z);
            a1v.w = fmaf(w1, h1.w, a1v.w);
            a2v.x = fmaf(w2, h2.x, a2v.x);
            a2v.y = fmaf(w2, h2.y, a2v.y);
            a2v.z = fmaf(w2, h2.z, a2v.z);
            a2v.w = fmaf(w2, h2.w, a2v.w);
            a3v.x = fmaf(w3, h3.x, a3v.x);
            a3v.y = fmaf(w3, h3.y, a3v.y);
            a3v.z = fmaf(w3, h3.z, a3v.z);
            a3v.w = fmaf(w3, h3.w, a3v.w);
            a4v.x = fmaf(w4, h4.x, a4v.x);
            a4v.y = fmaf(w4, h4.y, a4v.y);
            a4v.z = fmaf(w4, h4.z, a4v.z);
            a4v.w = fmaf(w4, h4.w, a4v.w);
        }
        for (; jp < cnt4; jp += 4) {
            float4 m1 = mp[jp + hi];
            float4 m2 = mp[jp + 2 + hi];
            int r1 = __float_as_int(m1.x);
            int r2 = __float_as_int(m2.x);
            float w1 = myq ? m1.z : m1.y;
            float w2 = myq ? m2.z : m2.y;
            float4 h1 = *(const float4*)&Hf[(size_t)r1 * 128 + colbase];
            float4 h2 = *(const float4*)&Hf[(size_t)r2 * 128 + colbase];
            a1v.x = fmaf(w1, h1.x, a1v.x);
            a1v.y = fmaf(w1, h1.y, a1v.y);
            a1v.z = fmaf(w1, h1.z, a1v.z);
            a1v.w = fmaf(w1, h1.w, a1v.w);
            a2v.x = fmaf(w2, h2.x, a2v.x);
            a2v.y = fmaf(w2, h2.y, a2v.y);
            a2v.z = fmaf(w2, h2.z, a2v.z);
            a2v.w = fmaf(w2, h2.w, a2v.w);
        }
    }
    a1v.x += a2v.x + a3v.x + a4v.x;
    a1v.y += a2v.y + a3v.y + a4v.y;
    a1v.z += a2v.z + a3v.z + a4v.z;
    a1v.w += a2v.w + a3v.w + a4v.w;
    a1v.x += __shfl_xor(a1v.x, 32);
    a1v.y += __shfl_xor(a1v.y, 32);
    a1v.z += __shfl_xor(a1v.z, 32);
    a1v.w += __shfl_xor(a1v.w, 32);
    for (int m = 32; m >= 1; m >>= 1) {
        z0 += __shfl_xor(z0, m);
        z1 += __shfl_xor(z1, m);
    }
    if (lane < 32) {
        float zinv = myq ? (1.f / z1) : (1.f / z0);
        float4 b = *(const float4*)&bias[colbase];
        float4 o;
        o.x = fmaf(a1v.x, zinv, b.x);
        o.y = fmaf(a1v.y, zinv, b.y);
        o.z = fmaf(a1v.z, zinv, b.z);
        o.w = fmaf(a1v.w, zinv, b.w);
        if (RELU) {
            o.x = fmaxf(o.x, 0.f);
            o.y = fmaxf(o.y, 0.f);
            o.z = fmaxf(o.z, 0.f);
            o.w = fmaxf(o.w, 0.f);
        }
        *(float4*)&Out[(size_t)wid * 128 + colbase] = o;
    }
}

// ---------------- aggregation M=64 ----------------
// Quarter-wave per edge (16 lanes x float4 = 256B row). LDS meta, 4 loads in flight.

template <int RELU>
__launch_bounds__(256)
__global__ void k_agg64(const int* __restrict__ ptr, const int* __restrict__ srcv,
                        const float* __restrict__ Hf, const float* __restrict__ als,
                        const float* __restrict__ ald, const float* __restrict__ bias,
                        float* __restrict__ Out, int n) {
    __shared__ float2 meta_s[4][64];
    int tid = threadIdx.x;
    int wslot = tid >> 6;
    int lane = tid & 63;
    int wid = blockIdx.x * 4 + wslot;
    if (wid >= n) return;
    float2* mp = meta_s[wslot];
    int start = ptr[wid], end = ptr[wid + 1];
    float ad0 = ald[wid];
    int q4 = lane >> 4;
    int colbase = (lane & 15) * 4;
    float z0 = 0.f;
    float4 a1v = make_float4(0.f, 0.f, 0.f, 0.f);
    float4 a2v = make_float4(0.f, 0.f, 0.f, 0.f);
    float4 a3v = make_float4(0.f, 0.f, 0.f, 0.f);
    float4 a4v = make_float4(0.f, 0.f, 0.f, 0.f);

    for (int base = start; base < end; base += 64) {
        int i = base + lane;
        int s_l = 0;
        float ex0 = 0.f;
        if (i < end) {
            s_l = srcv[i];
            float e0 = als[s_l] + ad0;
            e0 = e0 > 0.f ? e0 : NEG_SLOPE * e0;
            ex0 = __expf(e0);
        }
        z0 += ex0;
        mp[lane] = make_float2(__int_as_float(s_l), ex0);
        int cntj = min(64, end - base);
        int cnt4 = (cntj + 3) & ~3;
        int jp = 0;
        for (; jp + 16 <= cnt4; jp += 16) {
            float2 m1 = mp[jp + q4];
            float2 m2 = mp[jp + 4 + q4];
            float2 m3 = mp[jp + 8 + q4];
            float2 m4 = mp[jp + 12 + q4];
            int r1 = __float_as_int(m1.x);
            int r2 = __float_as_int(m2.x);
            int r3 = __float_as_int(m3.x);
            int r4 = __float_as_int(m4.x);
            float4 h1 = *(const float4*)&Hf[(size_t)r1 * 64 + colbase];
            float4 h2 = *(const float4*)&Hf[(size_t)r2 * 64 + colbase];
            float4 h3 = *(const float4*)&Hf[(size_t)r3 * 64 + colbase];
            float4 h4 = *(const float4*)&Hf[(size_t)r4 * 64 + colbase];
            a1v.x = fmaf(m1.y, h1.x, a1v.x);
            a1v.y = fmaf(m1.y, h1.y, a1v.y);
            a1v.z = fmaf(m1.y, h1.z, a1v.z);
            a1v.w = fmaf(m1.y, h1.w, a1v.w);
            a2v.x = fmaf(m2.y, h2.x, a2v.x);
            a2v.y = fmaf(m2.y, h2.y, a2v.y);
            a2v.z = fmaf(m2.y, h2.z, a2v.z);
            a2v.w = fmaf(m2.y, h2.w, a2v.w);
            a3v.x = fmaf(m3.y, h3.x, a3v.x);
            a3v.y = fmaf(m3.y, h3.y, a3v.y);
            a3v.z = fmaf(m3.y, h3.z, a3v.z);
            a3v.w = fmaf(m3.y, h3.w, a3v.w);
            a4v.x = fmaf(m4.y, h4.x, a4v.x);
            a4v.y = fmaf(m4.y, h4.y, a4v.y);
            a4v.z = fmaf(m4.y, h4.z, a4v.z);
            a4v.w = fmaf(m4.y, h4.w, a4v.w);
        }
        for (; jp < cnt4; jp += 4) {
            float2 m1 = mp[jp + q4];
            int r1 = __float_as_int(m1.x);
            float4 h1 = *(const float4*)&Hf[(size_t)r1 * 64 + colbase];
            a1v.x = fmaf(m1.y, h1.x, a1v.x);
            a1v.y = fmaf(m1.y, h1.y, a1v.y);
            a1v.z = fmaf(m1.y, h1.z, a1v.z);
            a1v.w = fmaf(m1.y, h1.w, a1v.w);
        }
    }
    a1v.x += a2v.x + a3v.x + a4v.x;
    a1v.y += a2v.y + a3v.y + a4v.y;
    a1v.z += a2v.z + a3v.z + a4v.z;
    a1v.w += a2v.w + a3v.w + a4v.w;
    a1v.x += __shfl_xor(a1v.x, 32);
    a1v.y += __shfl_xor(a1v.y, 32);
    a1v.z += __shfl_xor(a1v.z, 32);
    a1v.w += __shfl_xor(a1v.w, 32);
    a1v.x += __shfl_xor(a1v.x, 16);
    a1v.y += __shfl_xor(a1v.y, 16);
    a1v.z += __shfl_xor(a1v.z, 16);
    a1v.w += __shfl_xor(a1v.w, 16);
    for (int m = 32; m >= 1; m >>= 1) z0 += __shfl_xor(z0, m);
    if (lane < 16) {
        float zinv = 1.f / z0;
        float4 b = *(const float4*)&bias[colbase];
        float4 o;
        o.x = fmaf(a1v.x, zinv, b.x);
        o.y = fmaf(a1v.y, zinv, b.y);
        o.z = fmaf(a1v.z, zinv, b.z);
        o.w = fmaf(a1v.w, zinv, b.w);
        if (RELU) {
            o.x = fmaxf(o.x, 0.f);
            o.y = fmaxf(o.y, 0.f);
            o.z = fmaxf(o.z, 0.f);
            o.w = fmaxf(o.w, 0.f);
        }
        *(float4*)&Out[(size_t)wid * 64 + colbase] = o;
    }
}

// ---------------- launch ----------------

extern "C" void kernel_launch(void* const* d_in, const int* in_sizes, int n_in,
                              void* d_out, int out_size, void* d_ws, size_t ws_size,
                              hipStream_t stream) {
    const float* x = (const float*)d_in[0];
    const int* ei = (const int*)d_in[1];
    const float* W1 = (const float*)d_in[2];
    const float* as1 = (const float*)d_in[3];
    const float* ad1 = (const float*)d_in[4];
    const float* b1 = (const float*)d_in[5];
    const float* W2 = (const float*)d_in[6];
    const float* as2 = (const float*)d_in[7];
    const float* ad2 = (const float*)d_in[8];
    const float* b2 = (const float*)d_in[9];
    const float* W3 = (const float*)d_in[10];
    const float* as3 = (const float*)d_in[11];
    const float* ad3 = (const float*)d_in[12];
    const float* b3 = (const float*)d_in[13];

    const int N = in_sizes[0] / 128;
    const int E = in_sizes[1] / 2;
    const int NB = (N + BUK_SIZE - 1) / BUK_SIZE;

    char* p = (char*)d_ws;
    auto alloc = [&](size_t bytes) -> char* {
        char* r = p;
        p += (bytes + 255) & ~(size_t)255;
        return r;
    };
    int* g_cnt = (int*)alloc(256 * 4);
    int* bucket_off = (int*)alloc(257 * 4);
    int* buckets = (int*)alloc((size_t)NB * BUK_CAP * 4);
    int* csr_ptr = (int*)alloc((size_t)(N + 1) * 4);
    int* csr_src = (int*)alloc((size_t)(E + N) * 4);
    float* als = (float*)alloc((size_t)N * 2 * 4);
    float* aldv = (float*)alloc((size_t)N * 2 * 4);
    float* Hbuf = (float*)alloc((size_t)N * 128 * 4);
    float* Obuf = (float*)alloc((size_t)N * 128 * 4);

    const int nbGemm = (N + 127) / 128;
    const int nbAgg = (N + 3) / 4;
    const int nbTile = (E + 4095) / 4096;

    // ---- binned CSR build (shared by all 3 layers) ----
    k_zero<<<1, 256, 0, stream>>>(g_cnt, 256);
    k_binscatter<<<nbTile, 256, 0, stream>>>(ei, g_cnt, buckets, E, NB);
    k_bucket_scan<<<1, 256, 0, stream>>>(g_cnt, bucket_off, NB, N);
    k_csr<<<NB, 512, 0, stream>>>(g_cnt, bucket_off, buckets, csr_ptr, csr_src, N, NB);

    // ---- layer 1 (128 -> H2*C64, concat, relu) ----
    k_gemm<128><<<nbGemm, 256, 0, stream>>>(x, W1, as1, ad1, Hbuf, als, aldv, N);
    k_agg128<1><<<nbAgg, 256, 0, stream>>>(csr_ptr, csr_src, Hbuf, als, aldv, b1, Obuf, N);

    // ---- layer 2 (128 -> H2*C64, concat, relu) ----
    k_gemm<128><<<nbGemm, 256, 0, stream>>>(Obuf, W2, as2, ad2, Hbuf, als, aldv, N);
    k_agg128<1><<<nbAgg, 256, 0, stream>>>(csr_ptr, csr_src, Hbuf, als, aldv, b2, Obuf, N);

    // ---- layer 3 (128 -> H1*C64, mean==identity, no relu) ----
    k_gemm<64><<<nbGemm, 256, 0, stream>>>(Obuf, W3, as3, ad3, Hbuf, als, aldv, N);
    k_agg64<0><<<nbAgg, 256, 0, stream>>>(csr_ptr, csr_src, Hbuf, als, aldv, b3,
                                          (float*)d_out, N);
}

// Round 6
// 628.069 us; speedup vs baseline: 1.0262x; 1.0262x over previous
//
#include <hip/hip_runtime.h>
#include <hip/hip_bf16.h>

#define NEG_SLOPE 0.2f
#define BUK_SHIFT 9
#define BUK_SIZE 512
#define BUK_CAP 16384  // max edges per 512-node bucket (expected ~8.2K, sigma ~91)

// ---------------- binned CSR build ----------------

__global__ void k_zero(int* g_cnt, int nb) {
    int i = blockIdx.x * blockDim.x + threadIdx.x;
    if (i < nb) g_cnt[i] = 0;
}

// Tile of 4096 edges per block. LDS bucket counts -> one chunk-reserve atomic per
// (block,bucket) -> append packed (src<<9 | dst&511) to bucket. Appends are
// frontier-sequential per bucket => dense 64B lines (vs 4B random scatter).
__launch_bounds__(256)
__global__ void k_binscatter(const int* __restrict__ ei, int* g_cnt, int* buckets,
                             int E, int nb) {
    __shared__ int lcnt[256], lbase[256], lcur[256];
    int t = threadIdx.x;
    if (t < nb) {
        lcnt[t] = 0;
        lcur[t] = 0;
    }
    __syncthreads();
    int tile0 = blockIdx.x * 4096;
    int pk[16], bk[16];
#pragma unroll
    for (int k = 0; k < 16; k++) {
        int idx = tile0 + k * 256 + t;
        bk[k] = -1;
        if (idx < E) {
            int s = ei[idx];
            int d = ei[E + idx];
            bk[k] = d >> BUK_SHIFT;
            pk[k] = (s << BUK_SHIFT) | (d & (BUK_SIZE - 1));
            atomicAdd(&lcnt[bk[k]], 1);
        }
    }
    __syncthreads();
    if (t < nb && lcnt[t] > 0) lbase[t] = atomicAdd(&g_cnt[t], lcnt[t]);
    __syncthreads();
#pragma unroll
    for (int k = 0; k < 16; k++) {
        if (bk[k] >= 0) {
            int p = lbase[bk[k]] + atomicAdd(&lcur[bk[k]], 1);
            if (p < BUK_CAP) buckets[(bk[k] << 14) + p] = pk[k];
        }
    }
}

// exclusive scan over nb bucket totals (edges + self-loops), nb <= 256
__global__ void k_bucket_scan(const int* __restrict__ g_cnt, int* bucket_off, int nb, int n) {
    __shared__ int s[256];
    int t = threadIdx.x;
    int selfc = 0;
    if (t < nb) {
        int lo = t * BUK_SIZE;
        selfc = min(BUK_SIZE, n - lo);
    }
    int v = (t < nb) ? (min(g_cnt[t], BUK_CAP) + selfc) : 0;
    s[t] = v;
    __syncthreads();
    for (int off = 1; off < 256; off <<= 1) {
        int x = (t >= off) ? s[t - off] : 0;
        __syncthreads();
        s[t] += x;
        __syncthreads();
    }
    if (t < nb) bucket_off[t] = s[t] - v;  // exclusive
    if (t == nb - 1) bucket_off[nb] = s[t];
}

// One block per bucket: local per-node count + scan + scatter into the bucket's
// contiguous csr window (L2-resident, ~35KB). Also emits csr_ptr and self-loops.
__launch_bounds__(512)
__global__ void k_csr(const int* __restrict__ g_cnt, const int* __restrict__ bucket_off,
                      const int* __restrict__ buckets, int* csr_ptr, int* csr_src,
                      int n, int nb) {
    __shared__ int lcnt[512], lsc[512], lcur[512];
    int b = blockIdx.x;
    int t = threadIdx.x;
    int nodes = min(BUK_SIZE, n - b * BUK_SIZE);
    int cnt = min(g_cnt[b], BUK_CAP);
    int boff = bucket_off[b];
    const int* bp = &buckets[b << 14];
    lcnt[t] = 0;
    __syncthreads();
    for (int i = t; i < cnt; i += 512) atomicAdd(&lcnt[bp[i] & (BUK_SIZE - 1)], 1);
    __syncthreads();
    int myc = (t < nodes) ? (lcnt[t] + 1) : 0;
    lsc[t] = myc;
    __syncthreads();
    for (int off = 1; off < 512; off <<= 1) {
        int x = (t >= off) ? lsc[t - off] : 0;
        __syncthreads();
        lsc[t] += x;
        __syncthreads();
    }
    int excl = lsc[t] - myc;
    lcur[t] = excl;
    if (t < nodes) csr_ptr[b * BUK_SIZE + t] = boff + excl;
    if (b == nb - 1 && t == 0) csr_ptr[n] = bucket_off[nb];
    __syncthreads();
    for (int i = t; i < cnt; i += 512) {
        int v = bp[i];
        int ld = v & (BUK_SIZE - 1);
        int p = atomicAdd(&lcur[ld], 1);
        csr_src[boff + p] = v >> BUK_SHIFT;
    }
    if (t < nodes) {
        int p = atomicAdd(&lcur[t], 1);
        csr_src[boff + p] = b * BUK_SIZE + t;  // self loop
    }
}

// ---------------- GEMM + fused attention logits ----------------

template <int M>
__launch_bounds__(256)
__global__ void k_gemm(const float* __restrict__ X, const float* __restrict__ W,
                       const float* __restrict__ asrc, const float* __restrict__ adst,
                       float* __restrict__ Hout, float* __restrict__ als,
                       float* __restrict__ ald, int n) {
    const int WS = M + 4;
    const int CPT = M / 16;
    __shared__ float Xs[128 * 36];
    __shared__ float Ws[32 * (M + 4)];
    int t = threadIdx.x;
    int c_grp = t & 15;
    int r_grp = t >> 4;
    int c0 = c_grp * CPT;
    int rb = blockIdx.x * 128;

    float acc[8][CPT];
#pragma unroll
    for (int i = 0; i < 8; i++)
#pragma unroll
        for (int j = 0; j < CPT; j++) acc[i][j] = 0.f;

    for (int p = 0; p < 4; p++) {
        __syncthreads();
        {
            const int TPR = M / 4;
            int wc4 = t % TPR;
            int wr0 = t / TPR;
            for (int wr = wr0; wr < 32; wr += 256 / TPR) {
                float4 v = *(const float4*)&W[(size_t)(p * 32 + wr) * M + wc4 * 4];
                *(float4*)&Ws[wr * WS + wc4 * 4] = v;
            }
        }
        {
            int k4 = t & 7;
            int r0 = t >> 3;
            for (int r = r0; r < 128; r += 32) {
                int grow = rb + r;
                float4 v = make_float4(0.f, 0.f, 0.f, 0.f);
                if (grow < n) v = *(const float4*)&X[(size_t)grow * 128 + p * 32 + k4 * 4];
                *(float4*)&Xs[r * 36 + k4 * 4] = v;
            }
        }
        __syncthreads();
#pragma unroll 4
        for (int k = 0; k < 32; k++) {
            float xv[8];
#pragma unroll
            for (int i = 0; i < 8; i++) xv[i] = Xs[(r_grp + 16 * i) * 36 + k];
            float wv[CPT];
#pragma unroll
            for (int j4 = 0; j4 < CPT / 4; j4++)
                *(float4*)&wv[j4 * 4] = *(const float4*)&Ws[k * WS + c0 + j4 * 4];
#pragma unroll
            for (int i = 0; i < 8; i++)
#pragma unroll
                for (int j = 0; j < CPT; j++) acc[i][j] = fmaf(xv[i], wv[j], acc[i][j]);
        }
    }

    float av[CPT], dv[CPT];
#pragma unroll
    for (int j = 0; j < CPT; j++) {
        av[j] = asrc[c0 + j];
        dv[j] = adst[c0 + j];
    }
#pragma unroll
    for (int i = 0; i < 8; i++) {
        int row = rb + r_grp + 16 * i;
        float ps = 0.f, pd = 0.f;
#pragma unroll
        for (int j = 0; j < CPT; j++) {
            ps = fmaf(acc[i][j], av[j], ps);
            pd = fmaf(acc[i][j], dv[j], pd);
        }
        const int RED = (M == 128) ? 4 : 8;
        for (int m = 1; m <= RED; m <<= 1) {
            ps += __shfl_xor(ps, m);
            pd += __shfl_xor(pd, m);
        }
        if (row < n) {
#pragma unroll
            for (int j4 = 0; j4 < CPT / 4; j4++)
                *(float4*)&Hout[(size_t)row * M + c0 + j4 * 4] =
                    make_float4(acc[i][j4 * 4], acc[i][j4 * 4 + 1], acc[i][j4 * 4 + 2],
                                acc[i][j4 * 4 + 3]);
            if (M == 128) {
                if ((c_grp & 7) == 0) {
                    int hd = c_grp >> 3;
                    als[(size_t)row * 2 + hd] = ps;
                    ald[(size_t)row * 2 + hd] = pd;
                }
            } else {
                if (c_grp == 0) {
                    als[row] = ps;
                    ald[row] = pd;
                }
            }
        }
    }
}

// ---------------- aggregation M=128: one wave per (node, head) ----------------
// Quarter-wave (16 lanes x float4 = 256B = one head slice) per edge; 4 loads in
// flight; metadata broadcast = 2 bpermutes per 4 edges (no selects, no LDS).

template <int RELU>
__launch_bounds__(256)
__global__ void k_agg128(const int* __restrict__ ptr, const int* __restrict__ srcv,
                         const float* __restrict__ Hf, const float* __restrict__ als,
                         const float* __restrict__ ald, const float* __restrict__ bias,
                         float* __restrict__ Out, int n) {
    int gw = blockIdx.x * 4 + (threadIdx.x >> 6);
    int wid = gw >> 1;
    int h = gw & 1;
    int lane = threadIdx.x & 63;
    if (wid >= n) return;
    int start = ptr[wid], end = ptr[wid + 1];
    float adh = ald[(size_t)wid * 2 + h];
    int q = lane >> 4;
    int col = h * 64 + (lane & 15) * 4;
    float z = 0.f;
    float4 a1 = make_float4(0.f, 0.f, 0.f, 0.f);
    float4 a2 = make_float4(0.f, 0.f, 0.f, 0.f);
    float4 a3 = make_float4(0.f, 0.f, 0.f, 0.f);
    float4 a4 = make_float4(0.f, 0.f, 0.f, 0.f);

    for (int base = start; base < end; base += 64) {
        int i = base + lane;
        int s_l = 0;
        float exh = 0.f;
        if (i < end) {
            s_l = srcv[i];
            float e = als[(size_t)s_l * 2 + h] + adh;
            e = e > 0.f ? e : NEG_SLOPE * e;
            exh = __expf(e);
        }
        z += exh;
        int cntj = min(64, end - base);
        int cnt4 = (cntj + 3) & ~3;  // zero-padded lanes: exh=0, s_l=0 -> harmless
        int jp = 0;
        for (; jp + 16 <= cnt4; jp += 16) {
            int r1 = __shfl(s_l, jp + q);
            float w1 = __shfl(exh, jp + q);
            int r2 = __shfl(s_l, jp + 4 + q);
            float w2 = __shfl(exh, jp + 4 + q);
            int r3 = __shfl(s_l, jp + 8 + q);
            float w3 = __shfl(exh, jp + 8 + q);
            int r4 = __shfl(s_l, jp + 12 + q);
            float w4 = __shfl(exh, jp + 12 + q);
            float4 h1 = *(const float4*)&Hf[(size_t)r1 * 128 + col];
            float4 h2 = *(const float4*)&Hf[(size_t)r2 * 128 + col];
            float4 h3 = *(const float4*)&Hf[(size_t)r3 * 128 + col];
            float4 h4 = *(const float4*)&Hf[(size_t)r4 * 128 + col];
            a1.x = fmaf(w1, h1.x, a1.x);
            a1.y = fmaf(w1, h1.y, a1.y);
            a1.z = fmaf(w1, h1.z, a1.z);
            a1.w = fmaf(w1, h1.w, a1.w);
            a2.x = fmaf(w2, h2.x, a2.x);
            a2.y = fmaf(w2, h2.y, a2.y);
            a2.z = fmaf(w2, h2.z, a2.z);
            a2.w = fmaf(w2, h2.w, a2.w);
            a3.x = fmaf(w3, h3.x, a3.x);
            a3.y = fmaf(w3, h3.y, a3.y);
            a3.z = fmaf(w3, h3.z, a3.z);
            a3.w = fmaf(w3, h3.w, a3.w);
            a4.x = fmaf(w4, h4.x, a4.x);
            a4.y = fmaf(w4, h4.y, a4.y);
            a4.z = fmaf(w4, h4.z, a4.z);
            a4.w = fmaf(w4, h4.w, a4.w);
        }
        for (; jp < cnt4; jp += 4) {
            int r1 = __shfl(s_l, jp + q);
            float w1 = __shfl(exh, jp + q);
            float4 h1 = *(const float4*)&Hf[(size_t)r1 * 128 + col];
            a1.x = fmaf(w1, h1.x, a1.x);
            a1.y = fmaf(w1, h1.y, a1.y);
            a1.z = fmaf(w1, h1.z, a1.z);
            a1.w = fmaf(w1, h1.w, a1.w);
        }
    }
    a1.x += a2.x + a3.x + a4.x;
    a1.y += a2.y + a3.y + a4.y;
    a1.z += a2.z + a3.z + a4.z;
    a1.w += a2.w + a3.w + a4.w;
    // reduce across quarters (lanes with same lane&15)
    a1.x += __shfl_xor(a1.x, 16);
    a1.y += __shfl_xor(a1.y, 16);
    a1.z += __shfl_xor(a1.z, 16);
    a1.w += __shfl_xor(a1.w, 16);
    a1.x += __shfl_xor(a1.x, 32);
    a1.y += __shfl_xor(a1.y, 32);
    a1.z += __shfl_xor(a1.z, 32);
    a1.w += __shfl_xor(a1.w, 32);
    for (int m = 32; m >= 1; m >>= 1) z += __shfl_xor(z, m);
    if (lane < 16) {
        float zinv = 1.f / z;
        float4 b = *(const float4*)&bias[col];
        float4 o;
        o.x = fmaf(a1.x, zinv, b.x);
        o.y = fmaf(a1.y, zinv, b.y);
        o.z = fmaf(a1.z, zinv, b.z);
        o.w = fmaf(a1.w, zinv, b.w);
        if (RELU) {
            o.x = fmaxf(o.x, 0.f);
            o.y = fmaxf(o.y, 0.f);
            o.z = fmaxf(o.z, 0.f);
            o.w = fmaxf(o.w, 0.f);
        }
        *(float4*)&Out[(size_t)wid * 128 + col] = o;
    }
}

// ---------------- aggregation M=64: one wave per node ----------------
// Quarter-wave (16 lanes x float4 = 256B = full row) per edge; 4 loads in flight.

template <int RELU>
__launch_bounds__(256)
__global__ void k_agg64(const int* __restrict__ ptr, const int* __restrict__ srcv,
                        const float* __restrict__ Hf, const float* __restrict__ als,
                        const float* __restrict__ ald, const float* __restrict__ bias,
                        float* __restrict__ Out, int n) {
    int wid = blockIdx.x * 4 + (threadIdx.x >> 6);
    int lane = threadIdx.x & 63;
    if (wid >= n) return;
    int start = ptr[wid], end = ptr[wid + 1];
    float ad0 = ald[wid];
    int q = lane >> 4;
    int col = (lane & 15) * 4;
    float z = 0.f;
    float4 a1 = make_float4(0.f, 0.f, 0.f, 0.f);
    float4 a2 = make_float4(0.f, 0.f, 0.f, 0.f);
    float4 a3 = make_float4(0.f, 0.f, 0.f, 0.f);
    float4 a4 = make_float4(0.f, 0.f, 0.f, 0.f);

    for (int base = start; base < end; base += 64) {
        int i = base + lane;
        int s_l = 0;
        float ex0 = 0.f;
        if (i < end) {
            s_l = srcv[i];
            float e = als[s_l] + ad0;
            e = e > 0.f ? e : NEG_SLOPE * e;
            ex0 = __expf(e);
        }
        z += ex0;
        int cntj = min(64, end - base);
        int cnt4 = (cntj + 3) & ~3;
        int jp = 0;
        for (; jp + 16 <= cnt4; jp += 16) {
            int r1 = __shfl(s_l, jp + q);
            float w1 = __shfl(ex0, jp + q);
            int r2 = __shfl(s_l, jp + 4 + q);
            float w2 = __shfl(ex0, jp + 4 + q);
            int r3 = __shfl(s_l, jp + 8 + q);
            float w3 = __shfl(ex0, jp + 8 + q);
            int r4 = __shfl(s_l, jp + 12 + q);
            float w4 = __shfl(ex0, jp + 12 + q);
            float4 h1 = *(const float4*)&Hf[(size_t)r1 * 64 + col];
            float4 h2 = *(const float4*)&Hf[(size_t)r2 * 64 + col];
            float4 h3 = *(const float4*)&Hf[(size_t)r3 * 64 + col];
            float4 h4 = *(const float4*)&Hf[(size_t)r4 * 64 + col];
            a1.x = fmaf(w1, h1.x, a1.x);
            a1.y = fmaf(w1, h1.y, a1.y);
            a1.z = fmaf(w1, h1.z, a1.z);
            a1.w = fmaf(w1, h1.w, a1.w);
            a2.x = fmaf(w2, h2.x, a2.x);
            a2.y = fmaf(w2, h2.y, a2.y);
            a2.z = fmaf(w2, h2.z, a2.z);
            a2.w = fmaf(w2, h2.w, a2.w);
            a3.x = fmaf(w3, h3.x, a3.x);
            a3.y = fmaf(w3, h3.y, a3.y);
            a3.z = fmaf(w3, h3.z, a3.z);
            a3.w = fmaf(w3, h3.w, a3.w);
            a4.x = fmaf(w4, h4.x, a4.x);
            a4.y = fmaf(w4, h4.y, a4.y);
            a4.z = fmaf(w4, h4.z, a4.z);
            a4.w = fmaf(w4, h4.w, a4.w);
        }
        for (; jp < cnt4; jp += 4) {
            int r1 = __shfl(s_l, jp + q);
            float w1 = __shfl(ex0, jp + q);
            float4 h1 = *(const float4*)&Hf[(size_t)r1 * 64 + col];
            a1.x = fmaf(w1, h1.x, a1.x);
            a1.y = fmaf(w1, h1.y, a1.y);
            a1.z = fmaf(w1, h1.z, a1.z);
            a1.w = fmaf(w1, h1.w, a1.w);
        }
    }
    a1.x += a2.x + a3.x + a4.x;
    a1.y += a2.y + a3.y + a4.y;
    a1.z += a2.z + a3.z + a4.z;
    a1.w += a2.w + a3.w + a4.w;
    a1.x += __shfl_xor(a1.x, 16);
    a1.y += __shfl_xor(a1.y, 16);
    a1.z += __shfl_xor(a1.z, 16);
    a1.w += __shfl_xor(a1.w, 16);
    a1.x += __shfl_xor(a1.x, 32);
    a1.y += __shfl_xor(a1.y, 32);
    a1.z += __shfl_xor(a1.z, 32);
    a1.w += __shfl_xor(a1.w, 32);
    for (int m = 32; m >= 1; m >>= 1) z += __shfl_xor(z, m);
    if (lane < 16) {
        float zinv = 1.f / z;
        float4 b = *(const float4*)&bias[col];
        float4 o;
        o.x = fmaf(a1.x, zinv, b.x);
        o.y = fmaf(a1.y, zinv, b.y);
        o.z = fmaf(a1.z, zinv, b.z);
        o.w = fmaf(a1.w, zinv, b.w);
        if (RELU) {
            o.x = fmaxf(o.x, 0.f);
            o.y = fmaxf(o.y, 0.f);
            o.z = fmaxf(o.z, 0.f);
            o.w = fmaxf(o.w, 0.f);
        }
        *(float4*)&Out[(size_t)wid * 64 + col] = o;
    }
}

// ---------------- launch ----------------

extern "C" void kernel_launch(void* const* d_in, const int* in_sizes, int n_in,
                              void* d_out, int out_size, void* d_ws, size_t ws_size,
                              hipStream_t stream) {
    const float* x = (const float*)d_in[0];
    const int* ei = (const int*)d_in[1];
    const float* W1 = (const float*)d_in[2];
    const float* as1 = (const float*)d_in[3];
    const float* ad1 = (const float*)d_in[4];
    const float* b1 = (const float*)d_in[5];
    const float* W2 = (const float*)d_in[6];
    const float* as2 = (const float*)d_in[7];
    const float* ad2 = (const float*)d_in[8];
    const float* b2 = (const float*)d_in[9];
    const float* W3 = (const float*)d_in[10];
    const float* as3 = (const float*)d_in[11];
    const float* ad3 = (const float*)d_in[12];
    const float* b3 = (const float*)d_in[13];

    const int N = in_sizes[0] / 128;
    const int E = in_sizes[1] / 2;
    const int NB = (N + BUK_SIZE - 1) / BUK_SIZE;

    char* p = (char*)d_ws;
    auto alloc = [&](size_t bytes) -> char* {
        char* r = p;
        p += (bytes + 255) & ~(size_t)255;
        return r;
    };
    int* g_cnt = (int*)alloc(256 * 4);
    int* bucket_off = (int*)alloc(257 * 4);
    int* buckets = (int*)alloc((size_t)NB * BUK_CAP * 4);
    int* csr_ptr = (int*)alloc((size_t)(N + 1) * 4);
    int* csr_src = (int*)alloc((size_t)(E + N) * 4);
    float* als = (float*)alloc((size_t)N * 2 * 4);
    float* aldv = (float*)alloc((size_t)N * 2 * 4);
    float* Hbuf = (float*)alloc((size_t)N * 128 * 4);
    float* Obuf = (float*)alloc((size_t)N * 128 * 4);

    const int nbGemm = (N + 127) / 128;
    const int nbAgg128 = (2 * N + 3) / 4;  // one wave per (node, head)
    const int nbAgg64 = (N + 3) / 4;       // one wave per node
    const int nbTile = (E + 4095) / 4096;

    // ---- binned CSR build (shared by all 3 layers) ----
    k_zero<<<1, 256, 0, stream>>>(g_cnt, 256);
    k_binscatter<<<nbTile, 256, 0, stream>>>(ei, g_cnt, buckets, E, NB);
    k_bucket_scan<<<1, 256, 0, stream>>>(g_cnt, bucket_off, NB, N);
    k_csr<<<NB, 512, 0, stream>>>(g_cnt, bucket_off, buckets, csr_ptr, csr_src, N, NB);

    // ---- layer 1 (128 -> H2*C64, concat, relu) ----
    k_gemm<128><<<nbGemm, 256, 0, stream>>>(x, W1, as1, ad1, Hbuf, als, aldv, N);
    k_agg128<1><<<nbAgg128, 256, 0, stream>>>(csr_ptr, csr_src, Hbuf, als, aldv, b1, Obuf, N);

    // ---- layer 2 (128 -> H2*C64, concat, relu) ----
    k_gemm<128><<<nbGemm, 256, 0, stream>>>(Obuf, W2, as2, ad2, Hbuf, als, aldv, N);
    k_agg128<1><<<nbAgg128, 256, 0, stream>>>(csr_ptr, csr_src, Hbuf, als, aldv, b2, Obuf, N);

    // ---- layer 3 (128 -> H1*C64, mean==identity, no relu) ----
    k_gemm<64><<<nbGemm, 256, 0, stream>>>(Obuf, W3, as3, ad3, Hbuf, als, aldv, N);
    k_agg64<0><<<nbAgg64, 256, 0, stream>>>(csr_ptr, csr_src, Hbuf, als, aldv, b3,
                                            (float*)d_out, N);
}